// Round 2
// baseline (2427.896 us; speedup 1.0000x reference)
//
#include <hip/hip_runtime.h>
#include <hip/hip_fp16.h>

typedef unsigned int uint;
typedef unsigned short ushort;

#define B 16
#define N 4096
#define S 1024          // NPOINT
#define K 32            // NSAMPLE
#define NPOS (B*S*K)    // 524288
#define NPAIR (NPOS/2)  // 262144

__device__ inline float h2f(ushort b) {
    __half h; *(ushort*)&h = b; return __half2float(h);
}
__device__ inline ushort f2h(float v) {
    __half h = __float2half(v); return *(ushort*)&h;
}

// ---------------- FPS: one block per batch ----------------
__global__ __launch_bounds__(1024) void fps_kernel(const float* __restrict__ xyz,
                                                   float* __restrict__ new_xyz) {
    const int b = blockIdx.x;
    const int t = threadIdx.x;
    __shared__ float lx[N], ly[N], lz[N];
    __shared__ float rv[16];
    __shared__ int   rj[16];
    __shared__ int   s_last;

    const float* xb = xyz + (size_t)b * N * 3;
    for (int i = t; i < N; i += 1024) {
        lx[i] = xb[i*3+0]; ly[i] = xb[i*3+1]; lz[i] = xb[i*3+2];
    }
    float dist[4] = {1e10f, 1e10f, 1e10f, 1e10f};
    __syncthreads();

    int last = 0;
    float* outb = new_xyz + (size_t)b * S * 3;
    for (int step = 0; step < S; ++step) {
        float cx = lx[last], cy = ly[last], cz = lz[last];
        if (t == 0) { outb[step*3+0] = cx; outb[step*3+1] = cy; outb[step*3+2] = cz; }

        float bv = -1.0f; int bj = 0x7fffffff;
        #pragma unroll
        for (int ii = 0; ii < 4; ++ii) {
            int j = t + ii * 1024;
            float dx = lx[j] - cx, dy = ly[j] - cy, dz = lz[j] - cz;
            float d = __fadd_rn(__fadd_rn(__fmul_rn(dx,dx), __fmul_rn(dy,dy)), __fmul_rn(dz,dz));
            float nd = fminf(dist[ii], d);
            dist[ii] = nd;
            if (nd > bv) { bv = nd; bj = j; }   // ascending j -> first max kept
        }
        #pragma unroll
        for (int off = 1; off < 64; off <<= 1) {
            float ov = __shfl_xor(bv, off);
            int   oj = __shfl_xor(bj, off);
            if (ov > bv || (ov == bv && oj < bj)) { bv = ov; bj = oj; }
        }
        int w = t >> 6;
        if ((t & 63) == 0) { rv[w] = bv; rj[w] = bj; }
        __syncthreads();
        if (t < 64) {
            float v2 = (t < 16) ? rv[t] : -1.0f;
            int   j2 = (t < 16) ? rj[t] : 0x7fffffff;
            #pragma unroll
            for (int off = 1; off < 16; off <<= 1) {
                float ov = __shfl_xor(v2, off);
                int   oj = __shfl_xor(j2, off);
                if (ov > v2 || (ov == v2 && oj < j2)) { v2 = ov; j2 = oj; }
            }
            if (t == 0) s_last = j2;
        }
        __syncthreads();
        last = s_last;
    }
}

// ---------------- transpose features (B,64,N) -> (B,N,64) ----------------
__global__ __launch_bounds__(256) void transpose_kernel(const float* __restrict__ feat,
                                                        float* __restrict__ featT) {
    const int b  = blockIdx.y;
    const int n0 = blockIdx.x * 64;
    __shared__ float tile[64][65];
    const int t  = threadIdx.x;
    const int tn = t & 63, r = t >> 6;
    for (int c = r; c < 64; c += 4)
        tile[c][tn] = feat[((size_t)b*64 + c)*N + n0 + tn];
    __syncthreads();
    for (int n = r; n < 64; n += 4)
        featT[((size_t)b*N + n0 + n)*64 + tn] = tile[tn][n];
}

// ---------------- ball query: one wave per center ----------------
__global__ __launch_bounds__(256) void ballq_kernel(const float* __restrict__ xyz,
                                                    const float* __restrict__ new_xyz,
                                                    int* __restrict__ idx) {
    const int wid  = (blockIdx.x * 256 + threadIdx.x) >> 6;   // center id
    const int lane = threadIdx.x & 63;
    const int b = wid >> 10;
    const float* xb = xyz + (size_t)b * N * 3;
    const float cx = new_xyz[(size_t)wid*3+0];
    const float cy = new_xyz[(size_t)wid*3+1];
    const float cz = new_xyz[(size_t)wid*3+2];
    int* ob = idx + (size_t)wid * K;

    const float R2 = 0.04f;  // float32(0.2*0.2) per JAX weak-type demotion
    int total = 0;
    int first = 0;
    bool gotfirst = false;
    for (int c0 = 0; c0 < N; c0 += 64) {
        const int j = c0 + lane;
        float dx = cx - xb[j*3+0];
        float dy = cy - xb[j*3+1];
        float dz = cz - xb[j*3+2];
        float d2 = __fadd_rn(__fadd_rn(__fmul_rn(dx,dx), __fmul_rn(dy,dy)), __fmul_rn(dz,dz));
        bool inr = d2 < R2;
        unsigned long long bal = __ballot(inr);
        if (bal) {
            if (!gotfirst) { first = c0 + __builtin_ctzll(bal); gotfirst = true; }
            int rank = __popcll(bal & ((1ull << lane) - 1ull));
            int pos = total + rank;
            if (inr && pos < K) ob[pos] = j;
            total += __popcll(bal);
            if (total >= K) break;
        }
    }
    for (int p2 = total + lane; p2 < K; p2 += 64) ob[p2] = first;
}

// ---------------- conv0: gather + 67->64, store fp16 channel-major ----------------
__global__ __launch_bounds__(256) void conv0_kernel(const float* __restrict__ xyz,
                                                    const float* __restrict__ new_xyz,
                                                    const float* __restrict__ featT,
                                                    const int* __restrict__ idx,
                                                    const float* __restrict__ w0,
                                                    const float* __restrict__ b0,
                                                    ushort* __restrict__ x0) {
    const int p  = blockIdx.x * 256 + threadIdx.x;  // position
    const int bs = p >> 5;                          // b*S+s
    const int b  = p >> 15;
    const int j  = idx[p];

    float fin[67];
    {
        const float* xp = xyz + ((size_t)b*N + (size_t)j)*3;
        fin[0] = xp[0] - new_xyz[(size_t)bs*3+0];
        fin[1] = xp[1] - new_xyz[(size_t)bs*3+1];
        fin[2] = xp[2] - new_xyz[(size_t)bs*3+2];
        const float4* fr = (const float4*)(featT + (((size_t)b*N + j) << 6));
        #pragma unroll
        for (int i = 0; i < 16; ++i) {
            float4 v = fr[i];
            fin[3+4*i] = v.x; fin[4+4*i] = v.y; fin[5+4*i] = v.z; fin[6+4*i] = v.w;
        }
    }
    #pragma unroll
    for (int og = 0; og < 64; og += 8) {
        float a[8];
        #pragma unroll
        for (int i = 0; i < 8; ++i) a[i] = b0[og+i];
        #pragma unroll
        for (int c = 0; c < 67; ++c) {
            float xv = fin[c];
            #pragma unroll
            for (int i = 0; i < 8; ++i)
                a[i] = fmaf(w0[(size_t)(og+i)*67 + c], xv, a[i]);
        }
        #pragma unroll
        for (int i = 0; i < 8; ++i)
            x0[(size_t)(og+i)*NPOS + p] = f2h(a[i]);
    }
}

// ---------------- per-channel sum / sumsq (C=64 layout, stride 64) ----------------
__global__ __launch_bounds__(256) void stats_kernel(const ushort* __restrict__ x,
                                                    float* __restrict__ st) {
    const int c = blockIdx.y;   // 0..63
    const uint2* xr = (const uint2*)(x + (size_t)c * NPOS);
    const int t = blockIdx.x * 256 + threadIdx.x;   // 0..8191
    float s = 0.f, q = 0.f;
    #pragma unroll
    for (int i = 0; i < 16; ++i) {
        uint2 u = xr[(size_t)i*8192 + t];
        float v0 = h2f((ushort)(u.x & 0xffff));
        float v1 = h2f((ushort)(u.x >> 16));
        float v2 = h2f((ushort)(u.y & 0xffff));
        float v3 = h2f((ushort)(u.y >> 16));
        s += v0 + v1 + v2 + v3;
        q += v0*v0 + v1*v1 + v2*v2 + v3*v3;
    }
    #pragma unroll
    for (int off = 32; off; off >>= 1) { s += __shfl_xor(s, off); q += __shfl_xor(q, off); }
    __shared__ float ls[4], lq[4];
    const int w = threadIdx.x >> 6;
    if ((threadIdx.x & 63) == 0) { ls[w] = s; lq[w] = q; }
    __syncthreads();
    if (threadIdx.x == 0) {
        s = ls[0]+ls[1]+ls[2]+ls[3];
        q = lq[0]+lq[1]+lq[2]+lq[3];
        atomicAdd(&st[c], s);
        atomicAdd(&st[64+c], q);
    }
}

// ---------------- fold BN into scale/shift (C=64) ----------------
__global__ void finalize_kernel(float* st, const float* __restrict__ g,
                                const float* __restrict__ be) {
    const int c = threadIdx.x;
    if (c < 64) {
        const float invn = 1.0f / (float)NPOS;
        float mean = st[c] * invn;
        float var  = st[64+c] * invn - mean*mean;
        float inv  = 1.0f / sqrtf(var + 1e-5f);
        float sc   = g[c] * inv;
        st[128+c] = sc;
        st[192+c] = fmaf(-mean, sc, be[c]);
    }
}

// ---------------- middle conv: normalize(prev)+relu then 64->64 ----------------
__global__ __launch_bounds__(256) void conv_mid_kernel(const ushort* __restrict__ xin,
                                                       const float* __restrict__ st,   // prev layer stats
                                                       const float* __restrict__ w,
                                                       const float* __restrict__ bias,
                                                       ushort* __restrict__ xout,
                                                       int wbase) {
    const int pp = blockIdx.x * 256 + threadIdx.x;   // pair index < NPAIR
    const float* scale = st + 128;
    const float* shift = st + 192;
    float a0[64], a1[64];
    #pragma unroll
    for (int o = 0; o < 64; ++o) { a0[o] = bias[wbase+o]; a1[o] = a0[o]; }
    const uint* xr = (const uint*)xin;
    #pragma unroll 4
    for (int c = 0; c < 64; ++c) {
        uint u = xr[(size_t)c * NPAIR + pp];
        float v0 = h2f((ushort)(u & 0xffff));
        float v1 = h2f((ushort)(u >> 16));
        float sc = scale[c], sh = shift[c];
        v0 = fmaxf(0.0f, fmaf(v0, sc, sh));
        v1 = fmaxf(0.0f, fmaf(v1, sc, sh));
        const float* wr = w + (size_t)wbase * 64 + c;
        #pragma unroll
        for (int o = 0; o < 64; ++o) {
            float wv = wr[o*64];
            a0[o] = fmaf(wv, v0, a0[o]);
            a1[o] = fmaf(wv, v1, a1[o]);
        }
    }
    uint* orow = (uint*)xout;
    #pragma unroll
    for (int o = 0; o < 64; ++o) {
        uint wd = (uint)f2h(a0[o]) | ((uint)f2h(a1[o]) << 16);
        orow[(size_t)o * NPAIR + pp] = wd;
    }
}

// ---------------- max-pool over K with BN+relu (64-channel half) ----------------
__global__ __launch_bounds__(256) void maxpool_kernel(const ushort* __restrict__ xh,
                                                      const float* __restrict__ st,   // this half's stats
                                                      float* __restrict__ out,
                                                      int cbase) {
    const int gid = blockIdx.x * 256 + threadIdx.x;   // < 64*16384
    const int c  = gid >> 14;       // 0..63 local channel
    const int bs = gid & 16383;
    const float sc = st[128 + c], sh = st[192 + c];
    const uint* xr = (const uint*)(xh + (size_t)c * NPOS + (size_t)bs * K);
    float m = -3.4e38f;
    #pragma unroll
    for (int i = 0; i < 16; ++i) {
        uint u = xr[i];
        m = fmaxf(m, fmaf(h2f((ushort)(u & 0xffff)), sc, sh));
        m = fmaxf(m, fmaf(h2f((ushort)(u >> 16)),    sc, sh));
    }
    m = fmaxf(m, 0.0f);   // relu(max) == max(relu) (monotone)
    const int b = bs >> 10, s = bs & 1023;
    out[((size_t)b*128 + cbase + c)*1024 + s] = m;
}

extern "C" void kernel_launch(void* const* d_in, const int* in_sizes, int n_in,
                              void* d_out, int out_size, void* d_ws, size_t ws_size,
                              hipStream_t stream) {
    const float* xyz      = (const float*)d_in[0];
    const float* features = (const float*)d_in[1];
    const float* w0 = (const float*)d_in[2];
    const float* b0 = (const float*)d_in[3];
    const float* g0 = (const float*)d_in[4];
    const float* be0= (const float*)d_in[5];
    const float* w1 = (const float*)d_in[6];
    const float* b1 = (const float*)d_in[7];
    const float* g1 = (const float*)d_in[8];
    const float* be1= (const float*)d_in[9];
    const float* w2 = (const float*)d_in[10];
    const float* b2 = (const float*)d_in[11];
    const float* g2 = (const float*)d_in[12];
    const float* be2= (const float*)d_in[13];

    float* out      = (float*)d_out;
    float* new_xyz  = out;              // (B,S,3)
    float* new_feat = out + (size_t)B*S*3;

    // Workspace layout (peak ~146 MB):
    //   [0,2MB)      idx
    //   [2,18MB)     featT
    //   [18MB,+4KB)  stats (4 regions x 256 floats)
    //   [A: 64MB)    x0, later reused as x2-half buffer
    //   [Bf: 64MB)   x1
    char* ws = (char*)d_ws;
    int*    idx   = (int*)ws;
    float*  featT = (float*)(ws + (2u<<20));
    float*  stats = (float*)(ws + (18u<<20));
    ushort* x0    = (ushort*)(ws + (18u<<20) + (1u<<16));
    ushort* x1    = x0 + (size_t)64 * NPOS;       // +64MB
    ushort* xh    = x0;                           // layer-2 half buffer aliases x0
    float* st0  = stats;            // C=64: sum,sumsq,scale,shift
    float* st1  = stats + 256;
    float* st2a = stats + 512;
    float* st2b = stats + 768;

    hipMemsetAsync(stats, 0, 1024 * sizeof(float), stream);

    fps_kernel<<<B, 1024, 0, stream>>>(xyz, new_xyz);
    transpose_kernel<<<dim3(N/64, B), 256, 0, stream>>>(features, featT);
    ballq_kernel<<<(B*S)/4, 256, 0, stream>>>(xyz, new_xyz, idx);
    conv0_kernel<<<NPOS/256, 256, 0, stream>>>(xyz, new_xyz, featT, idx, w0, b0, x0);

    stats_kernel<<<dim3(32, 64), 256, 0, stream>>>(x0, st0);
    finalize_kernel<<<1, 64, 0, stream>>>(st0, g0, be0);
    conv_mid_kernel<<<NPAIR/256, 256, 0, stream>>>(x0, st0, w1, b1, x1, 0);

    stats_kernel<<<dim3(32, 64), 256, 0, stream>>>(x1, st1);
    finalize_kernel<<<1, 64, 0, stream>>>(st1, g1, be1);

    // layer 2, half 0 (output channels 0..63) — xh aliases x0 (dead now)
    conv_mid_kernel<<<NPAIR/256, 256, 0, stream>>>(x1, st1, w2, b2, xh, 0);
    stats_kernel<<<dim3(32, 64), 256, 0, stream>>>(xh, st2a);
    finalize_kernel<<<1, 64, 0, stream>>>(st2a, g2, be2);
    maxpool_kernel<<<(64*B*S)/256, 256, 0, stream>>>(xh, st2a, new_feat, 0);

    // layer 2, half 1 (output channels 64..127)
    conv_mid_kernel<<<NPAIR/256, 256, 0, stream>>>(x1, st1, w2, b2, xh, 64);
    stats_kernel<<<dim3(32, 64), 256, 0, stream>>>(xh, st2b);
    finalize_kernel<<<1, 64, 0, stream>>>(st2b, g2 + 64, be2 + 64);
    maxpool_kernel<<<(64*B*S)/256, 256, 0, stream>>>(xh, st2b, new_feat, 64);
}

// Round 4
// 1691.460 us; speedup vs baseline: 1.4354x; 1.4354x over previous
//
#include <hip/hip_runtime.h>
#include <hip/hip_fp16.h>

typedef unsigned int uint;
typedef unsigned short ushort;
typedef unsigned long long ull;

#define B 16
#define N 4096
#define S 1024          // NPOINT
#define K 32            // NSAMPLE
#define NPOS (B*S*K)    // 524288
#define NPAIR (NPOS/2)  // 262144

__device__ inline float h2f(ushort b) {
    __half h; *(ushort*)&h = b; return __half2float(h);
}
__device__ inline ushort f2h(float v) {
    __half h = __float2half(v); return *(ushort*)&h;
}

// ---------------- FPS: one block (256 thr, 4 waves) per batch ----------------
// Coordinates live in registers (16 pts/thread); LDS copy only for centroid
// lookup. Per step: reg dist update + packed-u64 (dist,~j) max, 5-level
// ds_swizzle butterfly (xor 1,2,4,8,16), lanes 0/32 atomicMax into a 3-slot
// rotating LDS u64, ONE barrier, read slot -> read centroid.
__global__ __launch_bounds__(256) void fps_kernel(const float* __restrict__ xyz,
                                                  float* __restrict__ new_xyz) {
    const int b  = blockIdx.x;
    const int lt = threadIdx.x;          // 0..255
    __shared__ float lx[N], ly[N], lz[N];
    __shared__ ull slot[3];

    const float* xb = xyz + (size_t)b * N * 3;
    float px[16], py[16], pz[16], dist[16];
    #pragma unroll
    for (int p = 0; p < 16; ++p) {
        const int j = lt + (p << 8);
        float x = xb[j*3+0], y = xb[j*3+1], z = xb[j*3+2];
        lx[j] = x; ly[j] = y; lz[j] = z;
        px[p] = x; py[p] = y; pz[p] = z;
        dist[p] = 1e10f;
    }
    if (lt < 3) slot[lt] = 0ull;
    __syncthreads();

    float cx = lx[0], cy = ly[0], cz = lz[0];
    const uint njlt = ~(uint)lt;
    float* outb = new_xyz + (size_t)b * S * 3;

    int cur = 0;
    for (int s = 0; s < S; ++s) {
        if (lt == 0) { outb[s*3+0] = cx; outb[s*3+1] = cy; outb[s*3+2] = cz; }

        ull best = 0ull;
        #pragma unroll
        for (int p = 0; p < 16; ++p) {
            float dx = px[p] - cx, dy = py[p] - cy, dz = pz[p] - cz;
            float d  = __fadd_rn(__fadd_rn(__fmul_rn(dx,dx), __fmul_rn(dy,dy)), __fmul_rn(dz,dz));
            float nd = fminf(dist[p], d);
            dist[p] = nd;
            ull pk = ((ull)__float_as_uint(nd) << 32) | (ull)(uint)(njlt - (p << 8));
            if (pk > best) best = pk;
        }
        // in-wave butterfly over 32-lane groups: xor 1,2,4,8,16 via ds_swizzle
        {
            uint blo = (uint)best, bhi = (uint)(best >> 32);
            #define FPS_LVL(MASK) { \
                uint olo = (uint)__builtin_amdgcn_ds_swizzle((int)blo, MASK); \
                uint ohi = (uint)__builtin_amdgcn_ds_swizzle((int)bhi, MASK); \
                ull o = ((ull)ohi << 32) | (ull)olo; \
                if (o > best) { best = o; bhi = ohi; blo = olo; } }
            FPS_LVL(0x041F)   // xor 1
            FPS_LVL(0x081F)   // xor 2
            FPS_LVL(0x101F)   // xor 4
            FPS_LVL(0x201F)   // xor 8
            FPS_LVL(0x401F)   // xor 16
            #undef FPS_LVL
        }
        if ((lt & 31) == 0) atomicMax(&slot[cur], best);
        int nxt = cur + 1; if (nxt == 3) nxt = 0;
        if (lt == 0) slot[nxt] = 0ull;   // last read 2 barriers ago; next atomic after this barrier
        __syncthreads();
        ull pk = slot[cur];
        int last = (int)(~(uint)pk);     // lo32 = ~j exactly
        cx = lx[last]; cy = ly[last]; cz = lz[last];
        cur = nxt;
    }
}

// ---------------- transpose features (B,64,N) -> (B,N,64) ----------------
__global__ __launch_bounds__(256) void transpose_kernel(const float* __restrict__ feat,
                                                        float* __restrict__ featT) {
    const int b  = blockIdx.y;
    const int n0 = blockIdx.x * 64;
    __shared__ float tile[64][65];
    const int t  = threadIdx.x;
    const int tn = t & 63, r = t >> 6;
    for (int c = r; c < 64; c += 4)
        tile[c][tn] = feat[((size_t)b*64 + c)*N + n0 + tn];
    __syncthreads();
    for (int n = r; n < 64; n += 4)
        featT[((size_t)b*N + n0 + n)*64 + tn] = tile[tn][n];
}

// ---------------- ball query: one wave per center ----------------
__global__ __launch_bounds__(256) void ballq_kernel(const float* __restrict__ xyz,
                                                    const float* __restrict__ new_xyz,
                                                    int* __restrict__ idx) {
    const int wid  = (blockIdx.x * 256 + threadIdx.x) >> 6;   // center id
    const int lane = threadIdx.x & 63;
    const int b = wid >> 10;
    const float* xb = xyz + (size_t)b * N * 3;
    const float cx = new_xyz[(size_t)wid*3+0];
    const float cy = new_xyz[(size_t)wid*3+1];
    const float cz = new_xyz[(size_t)wid*3+2];
    int* ob = idx + (size_t)wid * K;

    const float R2 = 0.04f;  // float32(0.2*0.2) per JAX weak-type demotion
    int total = 0;
    int first = 0;
    bool gotfirst = false;
    for (int c0 = 0; c0 < N; c0 += 64) {
        const int j = c0 + lane;
        float dx = cx - xb[j*3+0];
        float dy = cy - xb[j*3+1];
        float dz = cz - xb[j*3+2];
        float d2 = __fadd_rn(__fadd_rn(__fmul_rn(dx,dx), __fmul_rn(dy,dy)), __fmul_rn(dz,dz));
        bool inr = d2 < R2;
        unsigned long long bal = __ballot(inr);
        if (bal) {
            if (!gotfirst) { first = c0 + __builtin_ctzll(bal); gotfirst = true; }
            int rank = __popcll(bal & ((1ull << lane) - 1ull));
            int pos = total + rank;
            if (inr && pos < K) ob[pos] = j;
            total += __popcll(bal);
            if (total >= K) break;
        }
    }
    for (int p2 = total + lane; p2 < K; p2 += 64) ob[p2] = first;
}

// ---------------- conv0: gather + 67->64, store fp16 channel-major ----------------
__global__ __launch_bounds__(256) void conv0_kernel(const float* __restrict__ xyz,
                                                    const float* __restrict__ new_xyz,
                                                    const float* __restrict__ featT,
                                                    const int* __restrict__ idx,
                                                    const float* __restrict__ w0,
                                                    const float* __restrict__ b0,
                                                    ushort* __restrict__ x0) {
    const int p  = blockIdx.x * 256 + threadIdx.x;  // position
    const int bs = p >> 5;                          // b*S+s
    const int b  = p >> 15;
    const int j  = idx[p];

    float fin[67];
    {
        const float* xp = xyz + ((size_t)b*N + (size_t)j)*3;
        fin[0] = xp[0] - new_xyz[(size_t)bs*3+0];
        fin[1] = xp[1] - new_xyz[(size_t)bs*3+1];
        fin[2] = xp[2] - new_xyz[(size_t)bs*3+2];
        const float4* fr = (const float4*)(featT + (((size_t)b*N + j) << 6));
        #pragma unroll
        for (int i = 0; i < 16; ++i) {
            float4 v = fr[i];
            fin[3+4*i] = v.x; fin[4+4*i] = v.y; fin[5+4*i] = v.z; fin[6+4*i] = v.w;
        }
    }
    #pragma unroll
    for (int og = 0; og < 64; og += 8) {
        float a[8];
        #pragma unroll
        for (int i = 0; i < 8; ++i) a[i] = b0[og+i];
        #pragma unroll
        for (int c = 0; c < 67; ++c) {
            float xv = fin[c];
            #pragma unroll
            for (int i = 0; i < 8; ++i)
                a[i] = fmaf(w0[(size_t)(og+i)*67 + c], xv, a[i]);
        }
        #pragma unroll
        for (int i = 0; i < 8; ++i)
            x0[(size_t)(og+i)*NPOS + p] = f2h(a[i]);
    }
}

// ---------------- per-channel sum / sumsq (C=64 layout, stride 64) ----------------
__global__ __launch_bounds__(256) void stats_kernel(const ushort* __restrict__ x,
                                                    float* __restrict__ st) {
    const int c = blockIdx.y;   // 0..63
    const uint2* xr = (const uint2*)(x + (size_t)c * NPOS);
    const int t = blockIdx.x * 256 + threadIdx.x;   // 0..8191
    float s = 0.f, q = 0.f;
    #pragma unroll
    for (int i = 0; i < 16; ++i) {
        uint2 u = xr[(size_t)i*8192 + t];
        float v0 = h2f((ushort)(u.x & 0xffff));
        float v1 = h2f((ushort)(u.x >> 16));
        float v2 = h2f((ushort)(u.y & 0xffff));
        float v3 = h2f((ushort)(u.y >> 16));
        s += v0 + v1 + v2 + v3;
        q += v0*v0 + v1*v1 + v2*v2 + v3*v3;
    }
    #pragma unroll
    for (int off = 32; off; off >>= 1) { s += __shfl_xor(s, off); q += __shfl_xor(q, off); }
    __shared__ float ls[4], lq[4];
    const int w = threadIdx.x >> 6;
    if ((threadIdx.x & 63) == 0) { ls[w] = s; lq[w] = q; }
    __syncthreads();
    if (threadIdx.x == 0) {
        s = ls[0]+ls[1]+ls[2]+ls[3];
        q = lq[0]+lq[1]+lq[2]+lq[3];
        atomicAdd(&st[c], s);
        atomicAdd(&st[64+c], q);
    }
}

// ---------------- fold BN into scale/shift (C=64) ----------------
__global__ void finalize_kernel(float* st, const float* __restrict__ g,
                                const float* __restrict__ be) {
    const int c = threadIdx.x;
    if (c < 64) {
        const float invn = 1.0f / (float)NPOS;
        float mean = st[c] * invn;
        float var  = st[64+c] * invn - mean*mean;
        float inv  = 1.0f / sqrtf(var + 1e-5f);
        float sc   = g[c] * inv;
        st[128+c] = sc;
        st[192+c] = fmaf(-mean, sc, be[c]);
    }
}

// ---------------- middle conv: normalize(prev)+relu then 64->64 ----------------
__global__ __launch_bounds__(256) void conv_mid_kernel(const ushort* __restrict__ xin,
                                                       const float* __restrict__ st,   // prev layer stats
                                                       const float* __restrict__ w,
                                                       const float* __restrict__ bias,
                                                       ushort* __restrict__ xout,
                                                       int wbase) {
    const int pp = blockIdx.x * 256 + threadIdx.x;   // pair index < NPAIR
    const float* scale = st + 128;
    const float* shift = st + 192;
    float a0[64], a1[64];
    #pragma unroll
    for (int o = 0; o < 64; ++o) { a0[o] = bias[wbase+o]; a1[o] = a0[o]; }
    const uint* xr = (const uint*)xin;
    #pragma unroll 4
    for (int c = 0; c < 64; ++c) {
        uint u = xr[(size_t)c * NPAIR + pp];
        float v0 = h2f((ushort)(u & 0xffff));
        float v1 = h2f((ushort)(u >> 16));
        float sc = scale[c], sh = shift[c];
        v0 = fmaxf(0.0f, fmaf(v0, sc, sh));
        v1 = fmaxf(0.0f, fmaf(v1, sc, sh));
        const float* wr = w + (size_t)wbase * 64 + c;
        #pragma unroll
        for (int o = 0; o < 64; ++o) {
            float wv = wr[o*64];
            a0[o] = fmaf(wv, v0, a0[o]);
            a1[o] = fmaf(wv, v1, a1[o]);
        }
    }
    uint* orow = (uint*)xout;
    #pragma unroll
    for (int o = 0; o < 64; ++o) {
        uint wd = (uint)f2h(a0[o]) | ((uint)f2h(a1[o]) << 16);
        orow[(size_t)o * NPAIR + pp] = wd;
    }
}

// ---------------- max-pool over K with BN+relu (64-channel half) ----------------
__global__ __launch_bounds__(256) void maxpool_kernel(const ushort* __restrict__ xh,
                                                      const float* __restrict__ st,   // this half's stats
                                                      float* __restrict__ out,
                                                      int cbase) {
    const int gid = blockIdx.x * 256 + threadIdx.x;   // < 64*16384
    const int c  = gid >> 14;       // 0..63 local channel
    const int bs = gid & 16383;
    const float sc = st[128 + c], sh = st[192 + c];
    const uint* xr = (const uint*)(xh + (size_t)c * NPOS + (size_t)bs * K);
    float m = -3.4e38f;
    #pragma unroll
    for (int i = 0; i < 16; ++i) {
        uint u = xr[i];
        m = fmaxf(m, fmaf(h2f((ushort)(u & 0xffff)), sc, sh));
        m = fmaxf(m, fmaf(h2f((ushort)(u >> 16)),    sc, sh));
    }
    m = fmaxf(m, 0.0f);   // relu(max) == max(relu) (monotone)
    const int b = bs >> 10, s = bs & 1023;
    out[((size_t)b*128 + cbase + c)*1024 + s] = m;
}

extern "C" void kernel_launch(void* const* d_in, const int* in_sizes, int n_in,
                              void* d_out, int out_size, void* d_ws, size_t ws_size,
                              hipStream_t stream) {
    const float* xyz      = (const float*)d_in[0];
    const float* features = (const float*)d_in[1];
    const float* w0 = (const float*)d_in[2];
    const float* b0 = (const float*)d_in[3];
    const float* g0 = (const float*)d_in[4];
    const float* be0= (const float*)d_in[5];
    const float* w1 = (const float*)d_in[6];
    const float* b1 = (const float*)d_in[7];
    const float* g1 = (const float*)d_in[8];
    const float* be1= (const float*)d_in[9];
    const float* w2 = (const float*)d_in[10];
    const float* b2 = (const float*)d_in[11];
    const float* g2 = (const float*)d_in[12];
    const float* be2= (const float*)d_in[13];

    float* out      = (float*)d_out;
    float* new_xyz  = out;              // (B,S,3)
    float* new_feat = out + (size_t)B*S*3;

    // Workspace layout (peak ~146 MB):
    //   [0,2MB)      idx
    //   [2,18MB)     featT
    //   [18MB,+4KB)  stats (4 regions x 256 floats)
    //   [A: 64MB)    x0, later reused as x2-half buffer
    //   [Bf: 64MB)   x1
    char* ws = (char*)d_ws;
    int*    idx   = (int*)ws;
    float*  featT = (float*)(ws + (2u<<20));
    float*  stats = (float*)(ws + (18u<<20));
    ushort* x0    = (ushort*)(ws + (18u<<20) + (1u<<16));
    ushort* x1    = x0 + (size_t)64 * NPOS;       // +64MB
    ushort* xh    = x0;                           // layer-2 half buffer aliases x0
    float* st0  = stats;            // C=64: sum,sumsq,scale,shift
    float* st1  = stats + 256;
    float* st2a = stats + 512;
    float* st2b = stats + 768;

    hipMemsetAsync(stats, 0, 1024 * sizeof(float), stream);

    fps_kernel<<<B, 256, 0, stream>>>(xyz, new_xyz);
    transpose_kernel<<<dim3(N/64, B), 256, 0, stream>>>(features, featT);
    ballq_kernel<<<(B*S)/4, 256, 0, stream>>>(xyz, new_xyz, idx);
    conv0_kernel<<<NPOS/256, 256, 0, stream>>>(xyz, new_xyz, featT, idx, w0, b0, x0);

    stats_kernel<<<dim3(32, 64), 256, 0, stream>>>(x0, st0);
    finalize_kernel<<<1, 64, 0, stream>>>(st0, g0, be0);
    conv_mid_kernel<<<NPAIR/256, 256, 0, stream>>>(x0, st0, w1, b1, x1, 0);

    stats_kernel<<<dim3(32, 64), 256, 0, stream>>>(x1, st1);
    finalize_kernel<<<1, 64, 0, stream>>>(st1, g1, be1);

    // layer 2, half 0 (output channels 0..63) — xh aliases x0 (dead now)
    conv_mid_kernel<<<NPAIR/256, 256, 0, stream>>>(x1, st1, w2, b2, xh, 0);
    stats_kernel<<<dim3(32, 64), 256, 0, stream>>>(xh, st2a);
    finalize_kernel<<<1, 64, 0, stream>>>(st2a, g2, be2);
    maxpool_kernel<<<(64*B*S)/256, 256, 0, stream>>>(xh, st2a, new_feat, 0);

    // layer 2, half 1 (output channels 64..127)
    conv_mid_kernel<<<NPAIR/256, 256, 0, stream>>>(x1, st1, w2, b2, xh, 64);
    stats_kernel<<<dim3(32, 64), 256, 0, stream>>>(xh, st2b);
    finalize_kernel<<<1, 64, 0, stream>>>(st2b, g2 + 64, be2 + 64);
    maxpool_kernel<<<(64*B*S)/256, 256, 0, stream>>>(xh, st2b, new_feat, 64);
}